// Round 15
// baseline (1328.961 us; speedup 1.0000x reference)
//
#include <hip/hip_runtime.h>

static constexpr int N = 100000;
static constexpr int E = 3200000;
static constexpr int NFEAT = 512;
static constexpr int K = 10;

typedef _Float16 half8 __attribute__((ext_vector_type(8)));
typedef _Float16 half4v __attribute__((ext_vector_type(4)));
typedef float v2f __attribute__((ext_vector_type(2)));
typedef unsigned int uint2v __attribute__((ext_vector_type(2)));

// ---- workspace layout (bytes) ----
static constexpr size_t OFF_CNT    = 0;                    // N int
static constexpr size_t OFF_FILL   = 512ull * 1024;        // N int
static constexpr size_t OFF_ROWPTR = 1024ull * 1024;       // N+1 int
static constexpr size_t OFF_DINV   = 1536ull * 1024;       // N float
static constexpr size_t OFF_BSUM   = 2048ull * 1024;       // 128 int
static constexpr size_t OFF_EW     = 2560ull * 1024;       // E int = 12.8 MB
static constexpr size_t OFF_G16    = OFF_EW + (size_t)E * 4 + 1024;    // N*64 fp16
static constexpr size_t OFF_GA     = OFF_G16 + (size_t)N * 128 + 1024; // N*64 fp8
static constexpr size_t OFF_GB     = OFF_GA + (size_t)N * 64 + 1024;   // N*64 fp8
static constexpr size_t OFF_SCA    = OFF_GB + (size_t)N * 64 + 1024;   // N f32
static constexpr size_t OFF_SCB    = OFF_SCA + (size_t)N * 4 + 1024;   // N f32
static constexpr size_t OFF_H1     = OFF_SCB + (size_t)N * 4 + 1024;   // N*64 fp16

// fp8 byte -> float (e4m3)
__device__ inline float dec1(int b) {
  v2f p = __builtin_amdgcn_cvt_pk_f32_fp8(b, false);
  return p[0];
}

// ---------- degree count ----------
__global__ __launch_bounds__(256) void count_k(const int* __restrict__ dst,
                                               int* __restrict__ cnt) {
  int e = blockIdx.x * 256 + threadIdx.x;
  if (e < E) atomicAdd(&cnt[__builtin_nontemporal_load(dst + e)], 1);
}

__global__ __launch_bounds__(256) void dinv_k(const int* __restrict__ cnt,
                                              float* __restrict__ dinv) {
  int i = blockIdx.x * 256 + threadIdx.x;
  if (i < N) dinv[i] = 1.0f / sqrtf((float)(cnt[i] + 1));  // +1 self-loop
}

// ---------- exclusive scan (3 kernels) ----------
__device__ inline int wave_incl_scan(int x) {
  int lane = threadIdx.x & 63;
#pragma unroll
  for (int off = 1; off < 64; off <<= 1) {
    int y = __shfl_up(x, off, 64);
    if (lane >= off) x += y;
  }
  return x;
}

__global__ __launch_bounds__(256) void scan1_k(const int* __restrict__ cnt,
                                               int* __restrict__ rowptr,
                                               int* __restrict__ bsum) {
  __shared__ int wsum[4];
  int tid = threadIdx.x, wid = tid >> 6, lane = tid & 63;
  int base = blockIdx.x * 1024 + tid * 4;
  int4 v = {0, 0, 0, 0};
  if (base + 3 < N) {
    v = *(const int4*)(cnt + base);
  } else {
    if (base + 0 < N) v.x = cnt[base + 0];
    if (base + 1 < N) v.y = cnt[base + 1];
    if (base + 2 < N) v.z = cnt[base + 2];
    if (base + 3 < N) v.w = cnt[base + 3];
  }
  int tsum = v.x + v.y + v.z + v.w;
  int incl = wave_incl_scan(tsum);
  if (lane == 63) wsum[wid] = incl;
  __syncthreads();
  int wof = 0;
  for (int i = 0; i < wid; ++i) wof += wsum[i];
  int e0 = wof + incl - tsum;  // exclusive start for this thread
  if (base + 0 < N) rowptr[base + 0] = e0;
  if (base + 1 < N) rowptr[base + 1] = e0 + v.x;
  if (base + 2 < N) rowptr[base + 2] = e0 + v.x + v.y;
  if (base + 3 < N) rowptr[base + 3] = e0 + v.x + v.y + v.z;
  if (tid == 255) bsum[blockIdx.x] = wof + incl;  // block total
}

__global__ __launch_bounds__(128) void scan2_k(int* __restrict__ bsum) {
  __shared__ int w0sum;
  int tid = threadIdx.x, wid = tid >> 6, lane = tid & 63;
  int v = (tid < 98) ? bsum[tid] : 0;
  int incl = wave_incl_scan(v);
  if (wid == 0 && lane == 63) w0sum = incl;
  __syncthreads();
  int excl = incl - v + (wid ? w0sum : 0);
  if (tid < 98) bsum[tid] = excl;
}

__global__ __launch_bounds__(256) void scan3_k(int* __restrict__ rowptr,
                                               const int* __restrict__ bsum) {
  int i = blockIdx.x * 256 + threadIdx.x;
  if (i < N) rowptr[i] += bsum[blockIdx.x >> 2];
  if (i == 0) rowptr[N] = E;
}

// ---------- CSR fill, XCD-sliced + non-temporal streaming reads (R4) ----------
__global__ __launch_bounds__(256) void fill2_k(const int* __restrict__ src,
                                               const int* __restrict__ dst,
                                               const int* __restrict__ rowptr,
                                               int* __restrict__ fillc,
                                               int* __restrict__ es) {
  const int slice = blockIdx.x & 7;
  const int chunk = blockIdx.x >> 3;
  const int lo = slice * 12500;
  const int hi = lo + 12500;  // N == 8*12500
  int e = chunk * 4096 + threadIdx.x;
  const int eend = min(E, chunk * 4096 + 4096);
  for (; e < eend; e += 256) {
    int d = __builtin_nontemporal_load(dst + e);
    if (d >= lo && d < hi) {
      int pos = rowptr[d] + atomicAdd(&fillc[d], 1);
      es[pos] = __builtin_nontemporal_load(src + e);
    }
  }
}

// ---------- GEMM1: h1 = relu(x @ W1 + b1) -> fp16, [N,512]x[512,64] ----------
__global__ __launch_bounds__(256) void gemm1_k(const float* __restrict__ x,
                                               const float* __restrict__ W1,
                                               const float* __restrict__ b1,
                                               _Float16* __restrict__ h1) {
  __shared__ float xs[16][256];   // transposed x tile: xs[k][node]
  __shared__ float w1s[16 * 64];  // W1 tile
  const int tid = threadIdx.x;
  const int n0 = blockIdx.x * 256;
  const int tn = tid & 127;  // node pair: tn, tn+128
  const int jh = tid >> 7;   // j half: [jh*32, jh*32+32)
  float4 acca[8], accb[8];
#pragma unroll
  for (int i = 0; i < 8; ++i) {
    acca[i] = float4{0.f, 0.f, 0.f, 0.f};
    accb[i] = float4{0.f, 0.f, 0.f, 0.f};
  }
  const int rowA = min(n0 + tid, N - 1);
  const float* xr = x + (size_t)rowA * NFEAT;
  for (int k0 = 0; k0 < NFEAT; k0 += 16) {
    float4 a0 = *(const float4*)(xr + k0 + 0);
    float4 a1 = *(const float4*)(xr + k0 + 4);
    float4 a2 = *(const float4*)(xr + k0 + 8);
    float4 a3 = *(const float4*)(xr + k0 + 12);
    float4 wv = *(const float4*)(W1 + (size_t)k0 * 64 + tid * 4);
    __syncthreads();  // previous iteration's reads complete
    xs[0][tid] = a0.x;  xs[1][tid] = a0.y;  xs[2][tid] = a0.z;  xs[3][tid] = a0.w;
    xs[4][tid] = a1.x;  xs[5][tid] = a1.y;  xs[6][tid] = a1.z;  xs[7][tid] = a1.w;
    xs[8][tid] = a2.x;  xs[9][tid] = a2.y;  xs[10][tid] = a2.z; xs[11][tid] = a2.w;
    xs[12][tid] = a3.x; xs[13][tid] = a3.y; xs[14][tid] = a3.z; xs[15][tid] = a3.w;
    *(float4*)&w1s[tid * 4] = wv;
    __syncthreads();
#pragma unroll
    for (int kk = 0; kk < 16; ++kk) {
      float xa = xs[kk][tn];
      float xb = xs[kk][tn + 128];
      const float* wr = &w1s[kk * 64 + jh * 32];
#pragma unroll
      for (int jj = 0; jj < 8; ++jj) {
        float4 w4 = *(const float4*)(wr + jj * 4);
        acca[jj].x += xa * w4.x; acca[jj].y += xa * w4.y;
        acca[jj].z += xa * w4.z; acca[jj].w += xa * w4.w;
        accb[jj].x += xb * w4.x; accb[jj].y += xb * w4.y;
        accb[jj].z += xb * w4.z; accb[jj].w += xb * w4.w;
      }
    }
  }
  const int na = n0 + tn, nb = na + 128;
#pragma unroll
  for (int jj = 0; jj < 8; ++jj) {
    int j = jh * 32 + jj * 4;
    float4 bb = *(const float4*)(b1 + j);
    half4v ra, rb;
    ra[0] = (_Float16)fmaxf(acca[jj].x + bb.x, 0.f);
    ra[1] = (_Float16)fmaxf(acca[jj].y + bb.y, 0.f);
    ra[2] = (_Float16)fmaxf(acca[jj].z + bb.z, 0.f);
    ra[3] = (_Float16)fmaxf(acca[jj].w + bb.w, 0.f);
    rb[0] = (_Float16)fmaxf(accb[jj].x + bb.x, 0.f);
    rb[1] = (_Float16)fmaxf(accb[jj].y + bb.y, 0.f);
    rb[2] = (_Float16)fmaxf(accb[jj].z + bb.z, 0.f);
    rb[3] = (_Float16)fmaxf(accb[jj].w + bb.w, 0.f);
    if (na < N) *(half4v*)(h1 + (size_t)na * 64 + j) = ra;
    if (nb < N) *(half4v*)(h1 + (size_t)nb * 64 + j) = rb;
  }
}

// ---------- GEMM2: h0 = h1@W2+b2 ; out = temp0*h0 ; g16 = fp16(dinv*h0) -------
__global__ __launch_bounds__(256) void gemm2_k(const _Float16* __restrict__ h1,
                                               const float* __restrict__ W2,
                                               const float* __restrict__ b2,
                                               const float* __restrict__ temp,
                                               const float* __restrict__ dinv,
                                               _Float16* __restrict__ g16,
                                               float* __restrict__ out) {
  __shared__ float w2s[64 * 64];
  const int tid = threadIdx.x;
#pragma unroll
  for (int i = 0; i < 4; ++i)
    *(float4*)&w2s[(i * 256 + tid) * 4] = *(const float4*)(W2 + (size_t)(i * 256 + tid) * 4);
  __syncthreads();
  const int node = blockIdx.x * 256 + tid;
  if (node >= N) return;
  float4 acc[16];
#pragma unroll
  for (int c = 0; c < 16; ++c) acc[c] = *(const float4*)(b2 + c * 4);
  const _Float16* hr = h1 + (size_t)node * 64;
  for (int j0 = 0; j0 < 64; j0 += 8) {
    half8 hv = *(const half8*)(hr + j0);
#pragma unroll
    for (int l = 0; l < 8; ++l) {
      float hl = (float)hv[l];
      const float* wr = &w2s[(j0 + l) * 64];
#pragma unroll
      for (int c = 0; c < 16; ++c) {
        float4 w4 = *(const float4*)(wr + c * 4);
        acc[c].x += hl * w4.x; acc[c].y += hl * w4.y;
        acc[c].z += hl * w4.z; acc[c].w += hl * w4.w;
      }
    }
  }
  const float t0 = temp[0];
  const float di = dinv[node];
  float* op = out + (size_t)node * 64;
  _Float16* gp = g16 + (size_t)node * 64;
#pragma unroll
  for (int c = 0; c < 16; ++c) {
    const float4 a = acc[c];
    float4 o;
    o.x = t0 * a.x; o.y = t0 * a.y; o.z = t0 * a.z; o.w = t0 * a.w;
    *(float4*)(op + c * 4) = o;
    half4v g;
    g[0] = (_Float16)(di * a.x); g[1] = (_Float16)(di * a.y);
    g[2] = (_Float16)(di * a.z); g[3] = (_Float16)(di * a.w);
    *(half4v*)(gp + c * 4) = g;
  }
}

// ---------- scaled-fp8 state write (8-lane-group form, used by prop16) -------
__device__ inline void write_fp8_state(const float* S, float dd, int node, int l,
                                       unsigned int* __restrict__ gout,
                                       float* __restrict__ oscale) {
  float v[8];
#pragma unroll
  for (int i = 0; i < 8; ++i) v[i] = dd * S[i];
  float m = 0.f;
#pragma unroll
  for (int i = 0; i < 8; ++i) m = fmaxf(m, fabsf(v[i]));
#pragma unroll
  for (int off = 1; off < 8; off <<= 1) m = fmaxf(m, __shfl_xor(m, off, 64));
  const float esc = (m > 0.f) ? 240.0f / m : 0.f;
  if (l == 0) oscale[node] = m * (1.0f / 240.0f);
  unsigned int w0 = 0, w1 = 0;
  w0 = __builtin_amdgcn_cvt_pk_fp8_f32(v[0] * esc, v[1] * esc, w0, false);
  w0 = __builtin_amdgcn_cvt_pk_fp8_f32(v[2] * esc, v[3] * esc, w0, true);
  w1 = __builtin_amdgcn_cvt_pk_fp8_f32(v[4] * esc, v[5] * esc, w1, false);
  w1 = __builtin_amdgcn_cvt_pk_fp8_f32(v[6] * esc, v[7] * esc, w1, true);
  uint2v gw; gw.x = w0; gw.y = w1;
  *(uint2v*)(gout + (size_t)node * 16 + l * 2) = gw;
}

// ---------- hop 1: fp16 gathers (exact g0), writes scaled-fp8 g1 ----------
__global__ __launch_bounds__(256) void prop16_k(const _Float16* __restrict__ gin,
                                                unsigned int* __restrict__ gout,
                                                float* __restrict__ oscale,
                                                float* __restrict__ out,
                                                const int* __restrict__ rowptr,
                                                const int* __restrict__ es,
                                                const float* __restrict__ dinv,
                                                const float* __restrict__ temp) {
  const int tid = threadIdx.x;
  const int sub = tid >> 3;
  const int l = tid & 7;
  const int node = blockIdx.x * 32 + sub;
  const int rs = rowptr[node];
  const int re = rowptr[node + 1];
  const float di = dinv[node];
  const _Float16* __restrict__ gq = gin + l * 8;

  half8 sr = *(const half8*)(gq + (size_t)node * 64);
  float a0[8], a1[8], a2[8], a3[8];
#pragma unroll
  for (int i = 0; i < 8; ++i) {
    a0[i] = (float)sr[i];
    a1[i] = 0.f; a2[i] = 0.f; a3[i] = 0.f;
  }

  int e = rs;
  for (; e + 4 <= re; e += 4) {
    int s0 = es[e], s1 = es[e + 1], s2 = es[e + 2], s3 = es[e + 3];
    half8 r0 = *(const half8*)(gq + (size_t)s0 * 64);
    half8 r1 = *(const half8*)(gq + (size_t)s1 * 64);
    half8 r2 = *(const half8*)(gq + (size_t)s2 * 64);
    half8 r3 = *(const half8*)(gq + (size_t)s3 * 64);
#pragma unroll
    for (int i = 0; i < 8; ++i) {
      a0[i] += (float)r0[i];
      a1[i] += (float)r1[i];
      a2[i] += (float)r2[i];
      a3[i] += (float)r3[i];
    }
  }
  for (; e < re; ++e) {
    int s0 = es[e];
    half8 r0 = *(const half8*)(gq + (size_t)s0 * 64);
#pragma unroll
    for (int i = 0; i < 8; ++i) a0[i] += (float)r0[i];
  }

  float S[8];
#pragma unroll
  for (int i = 0; i < 8; ++i) S[i] = (a0[i] + a1[i]) + (a2[i] + a3[i]);

  const float th = temp[1] * di;
  const float dd = di * di;
  const size_t base = (size_t)node * 64 + l * 8;
  float4 o0 = *(const float4*)(out + base);
  float4 o1 = *(const float4*)(out + base + 4);
  o0.x += th * S[0]; o0.y += th * S[1]; o0.z += th * S[2]; o0.w += th * S[3];
  o1.x += th * S[4]; o1.y += th * S[5]; o1.z += th * S[6]; o1.w += th * S[7];
  *(float4*)(out + base) = o0;
  *(float4*)(out + base + 4) = o1;
  write_fp8_state(S, dd, node, l, gout, oscale);
}

// ---------- hops 2..K: wave-per-node, lane-per-feature fp8 gathers ----------
// One wave owns one node; lane f loads byte f of each gathered 64B row ->
// one coalesced line transaction per edge, ZERO divergence (bounds are
// wave-uniform scalars), 8-deep unroll = 8 gathers in flight per wave.
__global__ __launch_bounds__(256) void prop8_k(const unsigned char* __restrict__ gin,
                                               const float* __restrict__ iscale,
                                               unsigned char* __restrict__ gout,
                                               float* __restrict__ oscale,
                                               float* __restrict__ out,
                                               const int* __restrict__ rowptr,
                                               const int* __restrict__ es,
                                               const float* __restrict__ dinv,
                                               const float* __restrict__ temp,
                                               int kp1, int writeh) {
  const int lane = threadIdx.x & 63;
  const int node = blockIdx.x * 4 + (threadIdx.x >> 6);  // N % 4 == 0
  const int rs = __builtin_amdgcn_readfirstlane(rowptr[node]);
  const int re = __builtin_amdgcn_readfirstlane(rowptr[node + 1]);
  const float di = dinv[node];

  // self term
  float a0 = iscale[node] * dec1((int)gin[(size_t)node * 64 + lane]);
  float a1 = 0.f, a2 = 0.f, a3 = 0.f;
  float a4 = 0.f, a5 = 0.f, a6 = 0.f, a7 = 0.f;

  int e = rs;
  for (; e + 8 <= re; e += 8) {
    int s0 = es[e],     s1 = es[e + 1], s2 = es[e + 2], s3 = es[e + 3];
    int s4 = es[e + 4], s5 = es[e + 5], s6 = es[e + 6], s7 = es[e + 7];
    float c0 = iscale[s0], c1 = iscale[s1], c2 = iscale[s2], c3 = iscale[s3];
    float c4 = iscale[s4], c5 = iscale[s5], c6 = iscale[s6], c7 = iscale[s7];
    int b0 = gin[(size_t)s0 * 64 + lane];
    int b1 = gin[(size_t)s1 * 64 + lane];
    int b2 = gin[(size_t)s2 * 64 + lane];
    int b3 = gin[(size_t)s3 * 64 + lane];
    int b4 = gin[(size_t)s4 * 64 + lane];
    int b5 = gin[(size_t)s5 * 64 + lane];
    int b6 = gin[(size_t)s6 * 64 + lane];
    int b7 = gin[(size_t)s7 * 64 + lane];
    a0 += c0 * dec1(b0);
    a1 += c1 * dec1(b1);
    a2 += c2 * dec1(b2);
    a3 += c3 * dec1(b3);
    a4 += c4 * dec1(b4);
    a5 += c5 * dec1(b5);
    a6 += c6 * dec1(b6);
    a7 += c7 * dec1(b7);
  }
  for (; e < re; ++e) {
    int s0 = es[e];
    float c0 = iscale[s0];
    int b0 = gin[(size_t)s0 * 64 + lane];
    a0 += c0 * dec1(b0);
  }

  const float S = ((a0 + a1) + (a2 + a3)) + ((a4 + a5) + (a6 + a7));

  const float th = temp[kp1] * di;
  const size_t base = (size_t)node * 64 + lane;
  out[base] += th * S;
  if (writeh) {
    const float v = di * di * S;
    float m = fabsf(v);
#pragma unroll
    for (int off = 1; off < 64; off <<= 1) m = fmaxf(m, __shfl_xor(m, off, 64));
    const float esc = (m > 0.f) ? 240.0f / m : 0.f;
    if (lane == 0) oscale[node] = m * (1.0f / 240.0f);
    unsigned int w = __builtin_amdgcn_cvt_pk_fp8_f32(v * esc, v * esc, 0u, false);
    gout[base] = (unsigned char)(w & 0xFF);
  }
}

extern "C" void kernel_launch(void* const* d_in, const int* in_sizes, int n_in,
                              void* d_out, int out_size, void* d_ws, size_t ws_size,
                              hipStream_t stream) {
  const float* x = (const float*)d_in[0];
  const int* ei = (const int*)d_in[1];
  const float* W1 = (const float*)d_in[2];
  const float* b1 = (const float*)d_in[3];
  const float* W2 = (const float*)d_in[4];
  const float* b2 = (const float*)d_in[5];
  const float* temp = (const float*)d_in[6];
  const int* srcp = ei;       // edge_index[0]
  const int* dstp = ei + E;   // edge_index[1]

  unsigned char* ws = (unsigned char*)d_ws;
  int* cnt = (int*)(ws + OFF_CNT);
  int* fillc = (int*)(ws + OFF_FILL);
  int* rowptr = (int*)(ws + OFF_ROWPTR);
  float* dinv = (float*)(ws + OFF_DINV);
  int* bsum = (int*)(ws + OFF_BSUM);
  int* es = (int*)(ws + OFF_EW);
  _Float16* g16 = (_Float16*)(ws + OFF_G16);
  unsigned char* gA = (unsigned char*)(ws + OFF_GA);
  unsigned char* gB = (unsigned char*)(ws + OFF_GB);
  float* scA = (float*)(ws + OFF_SCA);
  float* scB = (float*)(ws + OFF_SCB);
  _Float16* h1 = (_Float16*)(ws + OFF_H1);
  float* out = (float*)d_out;

  hipMemsetAsync(cnt, 0, (size_t)N * 4, stream);
  hipMemsetAsync(fillc, 0, (size_t)N * 4, stream);

  count_k<<<E / 256, 256, 0, stream>>>(dstp, cnt);
  dinv_k<<<(N + 255) / 256, 256, 0, stream>>>(cnt, dinv);
  scan1_k<<<(N + 1023) / 1024, 256, 0, stream>>>(cnt, rowptr, bsum);
  scan2_k<<<1, 128, 0, stream>>>(bsum);
  scan3_k<<<(N + 255) / 256, 256, 0, stream>>>(rowptr, bsum);
  fill2_k<<<8 * 782, 256, 0, stream>>>(srcp, dstp, rowptr, fillc, es);

  gemm1_k<<<(N + 255) / 256, 256, 0, stream>>>(x, W1, b1, h1);
  gemm2_k<<<(N + 255) / 256, 256, 0, stream>>>(h1, W2, b2, temp, dinv, g16, out);

  // hop 1 from exact fp16 state; emits per-row-scaled fp8 state for hop 2
  prop16_k<<<N / 32, 256, 0, stream>>>(g16, (unsigned int*)gA, scA, out, rowptr,
                                       es, dinv, temp);

  const unsigned char* gin = gA;
  unsigned char* gout = gB;
  const float* sin = scA;
  float* sout = scB;
  for (int k = 1; k < K; ++k) {
    prop8_k<<<N / 4, 256, 0, stream>>>(gin, sin, gout, sout, out, rowptr, es,
                                       dinv, temp, k + 1, (k + 1 < K) ? 1 : 0);
    const unsigned char* tg = gin; gin = gout; gout = (unsigned char*)tg;
    const float* ts = sin; sin = sout; sout = (float*)ts;
  }
}

// Round 16
// 1026.179 us; speedup vs baseline: 1.2951x; 1.2951x over previous
//
#include <hip/hip_runtime.h>

static constexpr int N = 100000;
static constexpr int E = 3200000;
static constexpr int NFEAT = 512;
static constexpr int K = 10;

typedef _Float16 half8 __attribute__((ext_vector_type(8)));
typedef _Float16 half4v __attribute__((ext_vector_type(4)));
typedef float v2f __attribute__((ext_vector_type(2)));
typedef unsigned int uint2v __attribute__((ext_vector_type(2)));

// ---- workspace layout (bytes) ----
static constexpr size_t OFF_CNT    = 0;                               // N int
static constexpr size_t OFF_FILL   = 512ull * 1024;                   // N int
static constexpr size_t OFF_ROWPTR = 1024ull * 1024;                  // N+1 int
static constexpr size_t OFF_DINV   = 1536ull * 1024;                  // N float
static constexpr size_t OFF_BSUM   = 2048ull * 1024;                  // 128 int
static constexpr size_t OFF_EW     = 2560ull * 1024;                  // E int = 12.8 MB
static constexpr size_t OFF_G16    = OFF_EW + (size_t)E * 4 + 1024;   // N*64 fp16 (hop-0 state)
static constexpr size_t OFF_GA     = OFF_G16 + (size_t)N * 64 * 2 + 1024;  // N*64 fp8
static constexpr size_t OFF_GB     = OFF_GA + (size_t)N * 64 + 1024;       // N*64 fp8
static constexpr size_t OFF_SCA    = OFF_GB + (size_t)N * 64 + 1024;       // N f32
static constexpr size_t OFF_SCB    = OFF_SCA + (size_t)N * 4 + 1024;       // N f32
static constexpr size_t OFF_H1     = OFF_SCB + (size_t)N * 4 + 1024;       // N*64 fp16

// ---------- degree count ----------
__global__ __launch_bounds__(256) void count_k(const int* __restrict__ dst,
                                               int* __restrict__ cnt) {
  int e = blockIdx.x * 256 + threadIdx.x;
  if (e < E) atomicAdd(&cnt[__builtin_nontemporal_load(dst + e)], 1);
}

__global__ __launch_bounds__(256) void dinv_k(const int* __restrict__ cnt,
                                              float* __restrict__ dinv) {
  int i = blockIdx.x * 256 + threadIdx.x;
  if (i < N) dinv[i] = 1.0f / sqrtf((float)(cnt[i] + 1));  // +1 self-loop
}

// ---------- exclusive scan (3 kernels) ----------
__device__ inline int wave_incl_scan(int x) {
  int lane = threadIdx.x & 63;
#pragma unroll
  for (int off = 1; off < 64; off <<= 1) {
    int y = __shfl_up(x, off, 64);
    if (lane >= off) x += y;
  }
  return x;
}

__global__ __launch_bounds__(256) void scan1_k(const int* __restrict__ cnt,
                                               int* __restrict__ rowptr,
                                               int* __restrict__ bsum) {
  __shared__ int wsum[4];
  int tid = threadIdx.x, wid = tid >> 6, lane = tid & 63;
  int base = blockIdx.x * 1024 + tid * 4;
  int4 v = {0, 0, 0, 0};
  if (base + 3 < N) {
    v = *(const int4*)(cnt + base);
  } else {
    if (base + 0 < N) v.x = cnt[base + 0];
    if (base + 1 < N) v.y = cnt[base + 1];
    if (base + 2 < N) v.z = cnt[base + 2];
    if (base + 3 < N) v.w = cnt[base + 3];
  }
  int tsum = v.x + v.y + v.z + v.w;
  int incl = wave_incl_scan(tsum);
  if (lane == 63) wsum[wid] = incl;
  __syncthreads();
  int wof = 0;
  for (int i = 0; i < wid; ++i) wof += wsum[i];
  int e0 = wof + incl - tsum;  // exclusive start for this thread
  if (base + 0 < N) rowptr[base + 0] = e0;
  if (base + 1 < N) rowptr[base + 1] = e0 + v.x;
  if (base + 2 < N) rowptr[base + 2] = e0 + v.x + v.y;
  if (base + 3 < N) rowptr[base + 3] = e0 + v.x + v.y + v.z;
  if (tid == 255) bsum[blockIdx.x] = wof + incl;  // block total
}

__global__ __launch_bounds__(128) void scan2_k(int* __restrict__ bsum) {
  __shared__ int w0sum;
  int tid = threadIdx.x, wid = tid >> 6, lane = tid & 63;
  int v = (tid < 98) ? bsum[tid] : 0;
  int incl = wave_incl_scan(v);
  if (wid == 0 && lane == 63) w0sum = incl;
  __syncthreads();
  int excl = incl - v + (wid ? w0sum : 0);
  if (tid < 98) bsum[tid] = excl;
}

__global__ __launch_bounds__(256) void scan3_k(int* __restrict__ rowptr,
                                               const int* __restrict__ bsum) {
  int i = blockIdx.x * 256 + threadIdx.x;
  if (i < N) rowptr[i] += bsum[blockIdx.x >> 2];
  if (i == 0) rowptr[N] = E;
}

// ---------- CSR fill, XCD-sliced + non-temporal streaming reads (R4) ----------
__global__ __launch_bounds__(256) void fill2_k(const int* __restrict__ src,
                                               const int* __restrict__ dst,
                                               const int* __restrict__ rowptr,
                                               int* __restrict__ fillc,
                                               int* __restrict__ es) {
  const int slice = blockIdx.x & 7;
  const int chunk = blockIdx.x >> 3;
  const int lo = slice * 12500;
  const int hi = lo + 12500;  // N == 8*12500
  int e = chunk * 4096 + threadIdx.x;
  const int eend = min(E, chunk * 4096 + 4096);
  for (; e < eend; e += 256) {
    int d = __builtin_nontemporal_load(dst + e);
    if (d >= lo && d < hi) {
      int pos = rowptr[d] + atomicAdd(&fillc[d], 1);
      es[pos] = __builtin_nontemporal_load(src + e);
    }
  }
}

// ---------- GEMM1: h1 = relu(x @ W1 + b1) -> fp16, [N,512]x[512,64] ----------
__global__ __launch_bounds__(256) void gemm1_k(const float* __restrict__ x,
                                               const float* __restrict__ W1,
                                               const float* __restrict__ b1,
                                               _Float16* __restrict__ h1) {
  __shared__ float xs[16][256];   // transposed x tile: xs[k][node]
  __shared__ float w1s[16 * 64];  // W1 tile
  const int tid = threadIdx.x;
  const int n0 = blockIdx.x * 256;
  const int tn = tid & 127;  // node pair: tn, tn+128
  const int jh = tid >> 7;   // j half: [jh*32, jh*32+32)
  float4 acca[8], accb[8];
#pragma unroll
  for (int i = 0; i < 8; ++i) {
    acca[i] = float4{0.f, 0.f, 0.f, 0.f};
    accb[i] = float4{0.f, 0.f, 0.f, 0.f};
  }
  const int rowA = min(n0 + tid, N - 1);
  const float* xr = x + (size_t)rowA * NFEAT;
  for (int k0 = 0; k0 < NFEAT; k0 += 16) {
    float4 a0 = *(const float4*)(xr + k0 + 0);
    float4 a1 = *(const float4*)(xr + k0 + 4);
    float4 a2 = *(const float4*)(xr + k0 + 8);
    float4 a3 = *(const float4*)(xr + k0 + 12);
    float4 wv = *(const float4*)(W1 + (size_t)k0 * 64 + tid * 4);
    __syncthreads();  // previous iteration's reads complete
    xs[0][tid] = a0.x;  xs[1][tid] = a0.y;  xs[2][tid] = a0.z;  xs[3][tid] = a0.w;
    xs[4][tid] = a1.x;  xs[5][tid] = a1.y;  xs[6][tid] = a1.z;  xs[7][tid] = a1.w;
    xs[8][tid] = a2.x;  xs[9][tid] = a2.y;  xs[10][tid] = a2.z; xs[11][tid] = a2.w;
    xs[12][tid] = a3.x; xs[13][tid] = a3.y; xs[14][tid] = a3.z; xs[15][tid] = a3.w;
    *(float4*)&w1s[tid * 4] = wv;
    __syncthreads();
#pragma unroll
    for (int kk = 0; kk < 16; ++kk) {
      float xa = xs[kk][tn];
      float xb = xs[kk][tn + 128];
      const float* wr = &w1s[kk * 64 + jh * 32];
#pragma unroll
      for (int jj = 0; jj < 8; ++jj) {
        float4 w4 = *(const float4*)(wr + jj * 4);
        acca[jj].x += xa * w4.x; acca[jj].y += xa * w4.y;
        acca[jj].z += xa * w4.z; acca[jj].w += xa * w4.w;
        accb[jj].x += xb * w4.x; accb[jj].y += xb * w4.y;
        accb[jj].z += xb * w4.z; accb[jj].w += xb * w4.w;
      }
    }
  }
  const int na = n0 + tn, nb = na + 128;
#pragma unroll
  for (int jj = 0; jj < 8; ++jj) {
    int j = jh * 32 + jj * 4;
    float4 bb = *(const float4*)(b1 + j);
    half4v ra, rb;
    ra[0] = (_Float16)fmaxf(acca[jj].x + bb.x, 0.f);
    ra[1] = (_Float16)fmaxf(acca[jj].y + bb.y, 0.f);
    ra[2] = (_Float16)fmaxf(acca[jj].z + bb.z, 0.f);
    ra[3] = (_Float16)fmaxf(acca[jj].w + bb.w, 0.f);
    rb[0] = (_Float16)fmaxf(accb[jj].x + bb.x, 0.f);
    rb[1] = (_Float16)fmaxf(accb[jj].y + bb.y, 0.f);
    rb[2] = (_Float16)fmaxf(accb[jj].z + bb.z, 0.f);
    rb[3] = (_Float16)fmaxf(accb[jj].w + bb.w, 0.f);
    if (na < N) *(half4v*)(h1 + (size_t)na * 64 + j) = ra;
    if (nb < N) *(half4v*)(h1 + (size_t)nb * 64 + j) = rb;
  }
}

// ---------- GEMM2: h0 = h1@W2+b2 ; out = temp0*h0 ; g16 = fp16(dinv*h0) -------
__global__ __launch_bounds__(256) void gemm2_k(const _Float16* __restrict__ h1,
                                               const float* __restrict__ W2,
                                               const float* __restrict__ b2,
                                               const float* __restrict__ temp,
                                               const float* __restrict__ dinv,
                                               _Float16* __restrict__ g16,
                                               float* __restrict__ out) {
  __shared__ float w2s[64 * 64];
  const int tid = threadIdx.x;
#pragma unroll
  for (int i = 0; i < 4; ++i)
    *(float4*)&w2s[(i * 256 + tid) * 4] = *(const float4*)(W2 + (size_t)(i * 256 + tid) * 4);
  __syncthreads();
  const int node = blockIdx.x * 256 + tid;
  if (node >= N) return;
  float4 acc[16];
#pragma unroll
  for (int c = 0; c < 16; ++c) acc[c] = *(const float4*)(b2 + c * 4);
  const _Float16* hr = h1 + (size_t)node * 64;
  for (int j0 = 0; j0 < 64; j0 += 8) {
    half8 hv = *(const half8*)(hr + j0);
#pragma unroll
    for (int l = 0; l < 8; ++l) {
      float hl = (float)hv[l];
      const float* wr = &w2s[(j0 + l) * 64];
#pragma unroll
      for (int c = 0; c < 16; ++c) {
        float4 w4 = *(const float4*)(wr + c * 4);
        acc[c].x += hl * w4.x; acc[c].y += hl * w4.y;
        acc[c].z += hl * w4.z; acc[c].w += hl * w4.w;
      }
    }
  }
  const float t0 = temp[0];
  const float di = dinv[node];
  float* op = out + (size_t)node * 64;
  _Float16* gp = g16 + (size_t)node * 64;
#pragma unroll
  for (int c = 0; c < 16; ++c) {
    const float4 a = acc[c];
    float4 o;
    o.x = t0 * a.x; o.y = t0 * a.y; o.z = t0 * a.z; o.w = t0 * a.w;
    *(float4*)(op + c * 4) = o;
    half4v g;
    g[0] = (_Float16)(di * a.x); g[1] = (_Float16)(di * a.y);
    g[2] = (_Float16)(di * a.z); g[3] = (_Float16)(di * a.w);
    *(half4v*)(gp + c * 4) = g;
  }
}

// ---------- fp8 decode: 8 fp8 (uint2v) -> 8 floats ----------
__device__ inline void dec8(uint2v u, float* f) {
  v2f p0 = __builtin_amdgcn_cvt_pk_f32_fp8(u.x, false);
  v2f p1 = __builtin_amdgcn_cvt_pk_f32_fp8(u.x, true);
  v2f p2 = __builtin_amdgcn_cvt_pk_f32_fp8(u.y, false);
  v2f p3 = __builtin_amdgcn_cvt_pk_f32_fp8(u.y, true);
  f[0] = p0[0]; f[1] = p0[1]; f[2] = p1[0]; f[3] = p1[1];
  f[4] = p2[0]; f[5] = p2[1]; f[6] = p3[0]; f[7] = p3[1];
}

// ---------- scaled-fp8 state write (shared by both prop kernels) ----------
// Row-max mapped to 240 -> full e4m3 mantissa precision for every row;
// per-row decode scale stored in oscale[node] (lane 0 of the 8-lane group).
__device__ inline void write_fp8_state(const float* S, float dd, int node, int l,
                                       unsigned int* __restrict__ gout,
                                       float* __restrict__ oscale) {
  float v[8];
#pragma unroll
  for (int i = 0; i < 8; ++i) v[i] = dd * S[i];
  float m = 0.f;
#pragma unroll
  for (int i = 0; i < 8; ++i) m = fmaxf(m, fabsf(v[i]));
#pragma unroll
  for (int off = 1; off < 8; off <<= 1) m = fmaxf(m, __shfl_xor(m, off, 64));
  const float esc = (m > 0.f) ? 240.0f / m : 0.f;
  if (l == 0) oscale[node] = m * (1.0f / 240.0f);
  unsigned int w0 = 0, w1 = 0;
  w0 = __builtin_amdgcn_cvt_pk_fp8_f32(v[0] * esc, v[1] * esc, w0, false);
  w0 = __builtin_amdgcn_cvt_pk_fp8_f32(v[2] * esc, v[3] * esc, w0, true);
  w1 = __builtin_amdgcn_cvt_pk_fp8_f32(v[4] * esc, v[5] * esc, w1, false);
  w1 = __builtin_amdgcn_cvt_pk_fp8_f32(v[6] * esc, v[7] * esc, w1, true);
  uint2v gw; gw.x = w0; gw.y = w1;
  *(uint2v*)(gout + (size_t)node * 16 + l * 2) = gw;
}

// ---------- hop 1: fp16 gathers (exact g0), writes scaled-fp8 g1 ----------
// 8 lanes per node (8 fp16 = 16B/lane), 32 nodes per block.
__global__ __launch_bounds__(256) void prop16_k(const _Float16* __restrict__ gin,
                                                unsigned int* __restrict__ gout,
                                                float* __restrict__ oscale,
                                                float* __restrict__ out,
                                                const int* __restrict__ rowptr,
                                                const int* __restrict__ es,
                                                const float* __restrict__ dinv,
                                                const float* __restrict__ temp) {
  const int tid = threadIdx.x;
  const int sub = tid >> 3;
  const int l = tid & 7;
  const int node = blockIdx.x * 32 + sub;
  const int rs = rowptr[node];
  const int re = rowptr[node + 1];
  const float di = dinv[node];
  const _Float16* __restrict__ gq = gin + l * 8;

  half8 sr = *(const half8*)(gq + (size_t)node * 64);
  float a0[8], a1[8], a2[8], a3[8];
#pragma unroll
  for (int i = 0; i < 8; ++i) {
    a0[i] = (float)sr[i];
    a1[i] = 0.f; a2[i] = 0.f; a3[i] = 0.f;
  }

  int e = rs;
  for (; e + 4 <= re; e += 4) {
    int s0 = es[e], s1 = es[e + 1], s2 = es[e + 2], s3 = es[e + 3];
    half8 r0 = *(const half8*)(gq + (size_t)s0 * 64);
    half8 r1 = *(const half8*)(gq + (size_t)s1 * 64);
    half8 r2 = *(const half8*)(gq + (size_t)s2 * 64);
    half8 r3 = *(const half8*)(gq + (size_t)s3 * 64);
#pragma unroll
    for (int i = 0; i < 8; ++i) {
      a0[i] += (float)r0[i];
      a1[i] += (float)r1[i];
      a2[i] += (float)r2[i];
      a3[i] += (float)r3[i];
    }
  }
  for (; e < re; ++e) {
    int s0 = es[e];
    half8 r0 = *(const half8*)(gq + (size_t)s0 * 64);
#pragma unroll
    for (int i = 0; i < 8; ++i) a0[i] += (float)r0[i];
  }

  float S[8];
#pragma unroll
  for (int i = 0; i < 8; ++i) S[i] = (a0[i] + a1[i]) + (a2[i] + a3[i]);

  const float th = temp[1] * di;
  const float dd = di * di;
  const size_t base = (size_t)node * 64 + l * 8;
  float4 o0 = *(const float4*)(out + base);
  float4 o1 = *(const float4*)(out + base + 4);
  o0.x += th * S[0]; o0.y += th * S[1]; o0.z += th * S[2]; o0.w += th * S[3];
  o1.x += th * S[4]; o1.y += th * S[5]; o1.z += th * S[6]; o1.w += th * S[7];
  *(float4*)(out + base) = o0;
  *(float4*)(out + base + 4) = o1;
  write_fp8_state(S, dd, node, l, gout, oscale);
}

// ---------- hops 2..K: scaled-fp8 gathers (64B row = 1 line/edge) ----------
__global__ __launch_bounds__(256) void prop8_k(const unsigned int* __restrict__ gin,
                                               const float* __restrict__ iscale,
                                               unsigned int* __restrict__ gout,
                                               float* __restrict__ oscale,
                                               float* __restrict__ out,
                                               const int* __restrict__ rowptr,
                                               const int* __restrict__ es,
                                               const float* __restrict__ dinv,
                                               const float* __restrict__ temp,
                                               int kp1, int writeh) {
  const int tid = threadIdx.x;
  const int sub = tid >> 3;
  const int l = tid & 7;
  const int node = blockIdx.x * 32 + sub;
  const int rs = rowptr[node];
  const int re = rowptr[node + 1];
  const float di = dinv[node];
  const unsigned int* __restrict__ gq = gin + l * 2;

  // self term
  uint2v sv = *(const uint2v*)(gq + (size_t)node * 16);
  const float sci = iscale[node];
  float t8[8];
  dec8(sv, t8);
  float a0[8], a1[8], a2[8], a3[8];
#pragma unroll
  for (int i = 0; i < 8; ++i) {
    a0[i] = sci * t8[i];
    a1[i] = 0.f; a2[i] = 0.f; a3[i] = 0.f;
  }

  int e = rs;
  for (; e + 4 <= re; e += 4) {
    int s0 = es[e], s1 = es[e + 1], s2 = es[e + 2], s3 = es[e + 3];
    float sc0 = iscale[s0], sc1 = iscale[s1], sc2 = iscale[s2], sc3 = iscale[s3];
    uint2v u0 = *(const uint2v*)(gq + (size_t)s0 * 16);
    uint2v u1 = *(const uint2v*)(gq + (size_t)s1 * 16);
    uint2v u2 = *(const uint2v*)(gq + (size_t)s2 * 16);
    uint2v u3 = *(const uint2v*)(gq + (size_t)s3 * 16);
    float r0[8], r1[8], r2[8], r3[8];
    dec8(u0, r0); dec8(u1, r1); dec8(u2, r2); dec8(u3, r3);
#pragma unroll
    for (int i = 0; i < 8; ++i) {
      a0[i] += sc0 * r0[i];
      a1[i] += sc1 * r1[i];
      a2[i] += sc2 * r2[i];
      a3[i] += sc3 * r3[i];
    }
  }
  for (; e < re; ++e) {
    int s0 = es[e];
    float sc0 = iscale[s0];
    uint2v u0 = *(const uint2v*)(gq + (size_t)s0 * 16);
    float r0[8];
    dec8(u0, r0);
#pragma unroll
    for (int i = 0; i < 8; ++i) a0[i] += sc0 * r0[i];
  }

  float S[8];
#pragma unroll
  for (int i = 0; i < 8; ++i) S[i] = (a0[i] + a1[i]) + (a2[i] + a3[i]);

  const float th = temp[kp1] * di;
  const float dd = di * di;
  const size_t base = (size_t)node * 64 + l * 8;
  float4 o0 = *(const float4*)(out + base);
  float4 o1 = *(const float4*)(out + base + 4);
  o0.x += th * S[0]; o0.y += th * S[1]; o0.z += th * S[2]; o0.w += th * S[3];
  o1.x += th * S[4]; o1.y += th * S[5]; o1.z += th * S[6]; o1.w += th * S[7];
  *(float4*)(out + base) = o0;
  *(float4*)(out + base + 4) = o1;
  if (writeh) write_fp8_state(S, dd, node, l, gout, oscale);
}

extern "C" void kernel_launch(void* const* d_in, const int* in_sizes, int n_in,
                              void* d_out, int out_size, void* d_ws, size_t ws_size,
                              hipStream_t stream) {
  const float* x = (const float*)d_in[0];
  const int* ei = (const int*)d_in[1];
  const float* W1 = (const float*)d_in[2];
  const float* b1 = (const float*)d_in[3];
  const float* W2 = (const float*)d_in[4];
  const float* b2 = (const float*)d_in[5];
  const float* temp = (const float*)d_in[6];
  const int* srcp = ei;       // edge_index[0]
  const int* dstp = ei + E;   // edge_index[1]

  unsigned char* ws = (unsigned char*)d_ws;
  int* cnt = (int*)(ws + OFF_CNT);
  int* fillc = (int*)(ws + OFF_FILL);
  int* rowptr = (int*)(ws + OFF_ROWPTR);
  float* dinv = (float*)(ws + OFF_DINV);
  int* bsum = (int*)(ws + OFF_BSUM);
  int* es = (int*)(ws + OFF_EW);
  _Float16* g16 = (_Float16*)(ws + OFF_G16);
  unsigned int* gA = (unsigned int*)(ws + OFF_GA);
  unsigned int* gB = (unsigned int*)(ws + OFF_GB);
  float* scA = (float*)(ws + OFF_SCA);
  float* scB = (float*)(ws + OFF_SCB);
  _Float16* h1 = (_Float16*)(ws + OFF_H1);
  float* out = (float*)d_out;

  hipMemsetAsync(cnt, 0, (size_t)N * 4, stream);
  hipMemsetAsync(fillc, 0, (size_t)N * 4, stream);

  count_k<<<E / 256, 256, 0, stream>>>(dstp, cnt);
  dinv_k<<<(N + 255) / 256, 256, 0, stream>>>(cnt, dinv);
  scan1_k<<<(N + 1023) / 1024, 256, 0, stream>>>(cnt, rowptr, bsum);
  scan2_k<<<1, 128, 0, stream>>>(bsum);
  scan3_k<<<(N + 255) / 256, 256, 0, stream>>>(rowptr, bsum);
  fill2_k<<<8 * 782, 256, 0, stream>>>(srcp, dstp, rowptr, fillc, es);

  gemm1_k<<<(N + 255) / 256, 256, 0, stream>>>(x, W1, b1, h1);
  gemm2_k<<<(N + 255) / 256, 256, 0, stream>>>(h1, W2, b2, temp, dinv, g16, out);

  // hop 1 from exact fp16 state; emits scaled-fp8 state for hop 2
  prop16_k<<<N / 32, 256, 0, stream>>>(g16, gA, scA, out, rowptr, es, dinv, temp);

  const unsigned int* gin = gA;
  unsigned int* gout = gB;
  const float* sin = scA;
  float* sout = scB;
  for (int k = 1; k < K; ++k) {
    prop8_k<<<N / 32, 256, 0, stream>>>(gin, sin, gout, sout, out, rowptr, es,
                                        dinv, temp, k + 1, (k + 1 < K) ? 1 : 0);
    const unsigned int* tg = gin; gin = gout; gout = (unsigned int*)tg;
    const float* ts = sin; sin = sout; sout = (float*)ts;
  }
}